// Round 11
// baseline (2932.153 us; speedup 1.0000x reference)
//
#include <hip/hip_runtime.h>
#include <math.h>

#define TSEQ 500
#define BQ   200
#define DIN  300
#define H1   256
#define H2   300
#define K1   556          // both layers: 256 recurrent/o1 + 300 x/h2
#define KP   576          // 18 MFMA k-steps of 32; k 0..255 = state, 256..555 = x|h2
#define H1P  256          // h1 row stride (ushorts)
#define H2P  304          // h2 row stride (300 + 4 zero pad)
#define BQC  25           // batches per chunk (8 chunks * 25 = 200)
#define LB1  8            // L1 blocks per chunk (32 units each)
#define LBT  18           // blocks per chunk (8 L1 + 10 L2)
#define NBLK 144          // 8 chunks * 18

#define H1SLOT (BQ*H1P)   // 51200 ushorts per slot (triple-buffered)
#define H2SLOT (BQ*H2P)   // 60800

// ws byte offsets (16B aligned)
#define WS_H1   0         // ushort [3][200][256] = 307200 B
#define WS_H2   307200    // ushort [3][200][304] = 364800 B
#define WS_C1   672000    // float [256][200] (fallback path only)
#define WS_C2   876800    // float [320][200] (fallback path only)
#define WS_FLG  1132800   // 8 chunks * 128 B (18 int flags; only 8..17 used)
#define WS_MSET 1133824

// Sentinel: 4x bf16 0xFFFF (NaN). sigmoid/tanh outputs are finite in (-1,1)
// -> a published granule can never equal POISON.
#define POISON 0xFFFFFFFFFFFFFFFFull

typedef __attribute__((ext_vector_type(8))) short short8;
typedef __attribute__((ext_vector_type(4))) float f32x4;
typedef unsigned long long u64;

__device__ __forceinline__ float sigf(float v){ return 1.0f/(1.0f+__expf(-v)); }
__device__ __forceinline__ float tanhf_(float v){
    v = fminf(15.0f, fmaxf(-15.0f, v));
    float e = __expf(2.0f*v);
    return (e-1.0f)/(e+1.0f);
}
__device__ __forceinline__ unsigned short f2bf(float f){   // RNE, finite inputs
    unsigned int xx = __builtin_bit_cast(unsigned int, f);
    xx = (xx + 0x7FFFu + ((xx>>16)&1u)) >> 16;
    return (unsigned short)xx;
}
// SYSTEM scope (sc0 sc1): bypass L1/L2, serviced at the MALL coherence point.
__device__ __forceinline__ u64 ld8_sys(const void* p){
    return __hip_atomic_load((const u64*)p, __ATOMIC_RELAXED, __HIP_MEMORY_SCOPE_SYSTEM);
}
// RETURNING swap: vmcnt retires only when the MALL executed the RMW (plain
// sc0sc1 stores are posted -- round-4 race). asm-consume forces returning form.
__device__ __forceinline__ void pub8(u64* p, u64 v){
    u64 old = __hip_atomic_exchange(p, v, __ATOMIC_RELAXED, __HIP_MEMORY_SCOPE_SYSTEM);
    asm volatile("" :: "v"(old));
}

union U16B { short8 s8; u64 u[2]; unsigned short us[8]; };
union U8B  { u64 u; unsigned short us[4]; };

// ===== Poison-polling protocol (sentinel sync, 1 MALL RTT per read) =========
// Granule lifecycle per slot s: [init 0 or host-poison] -> in-loop POISON two
// iters before publish -> publish (overwrites poison) -> consumers poll !=
// POISON. Ordering proofs:
//  * poison issued right AFTER B1@it: B1 aggregates the block's full-panel
//    poll of slot it%3, which proves every same-layer block published it-1,
//    hence finished ITS staging reads of the slot being poisoned (WAR-safe).
//  * poison retires at B1@it+1's vmcnt drain -> applied before this block's
//    epilogue publish@it+1 into the same region (no poison-over-data).
//  * readers@it+2 are gated (via their polls) behind all blocks' B1@it+1,
//    so every poison is applied before they poll: no stale-data window.
//  * h1 slot 1 (published@0, read@1) has no in-loop poison opportunity ->
//    host pre-poisons it with memset 0xFF.
//  * L2 o1-readers of slot (it-1)%3 are covered by L1's end-of-iter flag wait.
// ============================================================================

__global__ __launch_bounds__(512, 2)
void lstm_mfma(const float* __restrict__ x, const int* __restrict__ lengths,
               const float* __restrict__ Wih1, const float* __restrict__ Whh1,
               const float* __restrict__ bih1, const float* __restrict__ bhh1,
               const float* __restrict__ Wih2, const float* __restrict__ Whh2,
               const float* __restrict__ bih2, const float* __restrict__ bhh2,
               float* __restrict__ out, char* __restrict__ wsb,
               int it_begin, int it_end, int coop)
{
    __shared__ unsigned short Al[32*KP];   // [batch][k] bf16, swizzled
    __shared__ float gl[128*33];           // gate exchange (wave-local rows)
    __shared__ float bias[128];
    __shared__ int lenl[32];

    const int tid = threadIdx.x;
    const int bid = blockIdx.x;
    const int mc  = bid & 7;               // batch chunk
    const int lbi = bid >> 3;              // 0..17 within chunk
    const bool l1 = lbi < LB1;
    const int ub  = (l1 ? lbi : lbi - LB1) * 32;   // unit base
    const int Hl  = l1 ? H1 : H2;

    unsigned short* h1s = (unsigned short*)(wsb + WS_H1);
    unsigned short* h2s = (unsigned short*)(wsb + WS_H2);
    float* c1 = (float*)(wsb + WS_C1);
    float* c2 = (float*)(wsb + WS_C2);
    int* flg = (int*)(wsb + WS_FLG + mc*128);      // [8..17]: L2 reads-done flags

    const int wave = tid >> 6, lane = tid & 63;
    const int fr = lane & 15, fg = lane >> 4;
    const int sw = fr & 7;

    // ---- weights -> VGPR, once. Row r = wave*16+fr = 4*u_local + gate.
    short8 wreg[18];
    {
        const int row = wave*16 + fr;
        const int u = row >> 2, g = row & 3;
        const int unit = ub + u;
        const bool vr = unit < Hl;
        const long grow = (long)g*Hl + unit;
        #pragma unroll
        for (int ks = 0; ks < 18; ++ks){
            unsigned short v8[8];
            #pragma unroll
            for (int j = 0; j < 8; ++j){
                int k = ks*32 + fg*8 + j;
                float v = 0.0f;
                if (vr && k < K1){
                    if (l1) v = (k < H1) ? Whh1[grow*H1 + k] : Wih1[grow*DIN + (k - H1)];
                    else    v = (k < H1) ? Wih2[grow*H1 + k] : Whh2[grow*H2 + (k - H1)];
                }
                v8[j] = f2bf(v);
            }
            wreg[ks] = *(short8*)v8;
        }
    }
    if (tid < 128){
        int u = tid >> 2, g = tid & 3, unit = ub + u;
        bias[tid] = (unit < Hl)
            ? ((l1?bih1:bih2)[g*Hl+unit] + (l1?bhh1:bhh2)[g*Hl+unit]) : 0.0f;
    }
    if (tid < 32) lenl[tid] = (tid < BQC) ? lengths[mc*BQC + tid] : 0;

    const unsigned short* arow0 = &Al[fr*KP];
    const unsigned short* arow1 = &Al[(16+fr)*KP];
    const int bg_e = mc*BQC + lane;        // epilogue batch (lane<BQC valid)
    const int unit4 = ub + wave*4;         // epilogue/publish/poison unit group

    float creg[4] = {0.f, 0.f, 0.f, 0.f};
    if (!coop && lane < 32){
        float* cs = l1 ? c1 : c2;
        #pragma unroll
        for (int i2 = 0; i2 < 4; ++i2) creg[i2] = cs[(unit4 + i2)*BQ + bg_e];
    }

    __syncthreads();

    for (int it = it_begin; it < it_end; ++it){
        const bool active = l1 ? (it < TSEQ) : (it >= 1);
        const int t = l1 ? it : it - 1;

        if (l1){
            if (active){
                // ---- stage x panel (k 256..575) -- cached loads ----
                #pragma unroll
                for (int i = 0; i < 3; ++i){
                    int e = tid + i*512;
                    if (e < 1280){
                        int bl = e/40, kcx = 32 + e - (e/40)*40;     // kcx 32..71
                        U16B v; v.u[0] = 0; v.u[1] = 0;
                        if (bl < BQC && kcx <= 69){
                            int bg = mc*BQC + bl;
                            const float* xp = x + ((size_t)bg*TSEQ + t)*DIN + (kcx*8 - 256);
                            float4 f0 = *(const float4*)xp;
                            v.us[0]=f2bf(f0.x); v.us[1]=f2bf(f0.y); v.us[2]=f2bf(f0.z); v.us[3]=f2bf(f0.w);
                            if (kcx <= 68){
                                float4 f1 = *(const float4*)(xp + 4);
                                v.us[4]=f2bf(f1.x); v.us[5]=f2bf(f1.y); v.us[6]=f2bf(f1.z); v.us[7]=f2bf(f1.w);
                            }
                        }
                        *(short8*)&Al[bl*KP + ((kcx ^ (bl&7))<<3)] = v.s8;
                    }
                }
                // ---- poll h1 slot it%3 directly (sentinel sync, 1 RTT) ----
                const unsigned short* h1p = h1s + (it%3)*H1SLOT;
                const int bl0 = tid>>5, kc0 = tid&31;
                const int bl1 = bl0 + 16;
                u64 a0=0, a1=0, a2=0, a3=0;
                const u64* p0 = (const u64*)(h1p + (size_t)(mc*BQC + bl0)*H1P + kc0*8);
                const u64* p2 = (const u64*)(h1p + (size_t)(mc*BQC + bl1)*H1P + kc0*8);
                const bool n0 = bl0 < BQC, n1 = bl1 < BQC;
                if (coop){
                    if (n0){ a0 = POISON; a1 = POISON; }
                    if (n1){ a2 = POISON; a3 = POISON; }
                    bool pend = n0 | n1;
                    while (pend){
                        if (a0 == POISON) a0 = ld8_sys(p0);
                        if (a1 == POISON) a1 = ld8_sys(p0 + 1);
                        if (a2 == POISON) a2 = ld8_sys(p2);
                        if (a3 == POISON) a3 = ld8_sys(p2 + 1);
                        pend = (a0==POISON)||(a1==POISON)||(a2==POISON)||(a3==POISON);
                        if (pend) __builtin_amdgcn_s_sleep(1);
                    }
                } else {
                    if (n0){ a0 = ld8_sys(p0); a1 = ld8_sys(p0 + 1); }
                    if (n1){ a2 = ld8_sys(p2); a3 = ld8_sys(p2 + 1); }
                }
                U16B w0; w0.u[0] = a0; w0.u[1] = a1;
                U16B w1; w1.u[0] = a2; w1.u[1] = a3;
                *(short8*)&Al[bl0*KP + ((kc0 ^ (bl0&7))<<3)] = w0.s8;
                *(short8*)&Al[bl1*KP + ((kc0 ^ (bl1&7))<<3)] = w1.s8;
            }
        } else {
            if (active){
                const unsigned short* h1p = h1s + (it%3)*H1SLOT;        // o1 source
                const unsigned short* h2p = h2s + ((it+2)%3)*H2SLOT;    // h2(it-1)
                const u64* pp[5]; bool qa[5], qb[5]; u64 va[5], vb[5];
                #pragma unroll
                for (int i = 0; i < 5; ++i){
                    const int e = tid + i*512;
                    const int bl = e/72, kc = e - (e/72)*72;
                    pp[i] = nullptr; qa[i] = false; qb[i] = false; va[i] = 0; vb[i] = 0;
                    if (e < 2304 && bl < BQC && kc < 70){
                        const int bg = mc*BQC + bl;
                        if (kc < 32){                          // o1 = masked h1
                            if (t < lenl[bl]){
                                pp[i] = (const u64*)(h1p + (size_t)bg*H1P + kc*8);
                                qa[i] = true; qb[i] = true;
                            }
                        } else {                               // h2 (kc=69: 2nd half = pad 0)
                            pp[i] = (const u64*)(h2p + (size_t)bg*H2P + (kc*8 - 256));
                            qa[i] = true; qb[i] = (kc < 69);
                        }
                    }
                }
                if (coop){
                    #pragma unroll
                    for (int i = 0; i < 5; ++i){ if (qa[i]) va[i] = POISON; if (qb[i]) vb[i] = POISON; }
                    bool pend = true;
                    while (pend){
                        pend = false;
                        #pragma unroll
                        for (int i = 0; i < 5; ++i){
                            if (qa[i] && va[i] == POISON){ va[i] = ld8_sys(pp[i]);     pend |= (va[i] == POISON); }
                            if (qb[i] && vb[i] == POISON){ vb[i] = ld8_sys(pp[i] + 1); pend |= (vb[i] == POISON); }
                        }
                        if (pend) __builtin_amdgcn_s_sleep(1);
                    }
                } else {
                    #pragma unroll
                    for (int i = 0; i < 5; ++i){
                        if (qa[i]) va[i] = ld8_sys(pp[i]);
                        if (qb[i]) vb[i] = ld8_sys(pp[i] + 1);
                    }
                }
                #pragma unroll
                for (int i = 0; i < 5; ++i){
                    const int e = tid + i*512;
                    if (e < 2304){
                        const int bl = e/72, kc = e - (e/72)*72;
                        U16B v; v.u[0] = va[i]; v.u[1] = vb[i];
                        *(short8*)&Al[bl*KP + ((kc ^ (bl&7))<<3)] = v.s8;
                    }
                }
            }
        }

        __syncthreads();   // B1 (full): staging LDS done + full-panel polls done
        if (!l1 && coop && tid == 0)   // reads-done flag (posted ok: progress only)
            __hip_atomic_store(&flg[lbi], it + 1, __ATOMIC_RELAXED,
                               __HIP_MEMORY_SCOPE_SYSTEM);

        // ---- poison next publish target (own region), gated by B1 (see top).
        //      Retires at B1@it+1 -> applied before epilogue publish@it+1.
        //      RTT fully hidden under the MFMA phase.
        if (coop && lane < BQC){
            if (l1){
                if (it + 1 < TSEQ)
                    pub8((u64*)&h1s[((it+2)%3)*H1SLOT + (size_t)bg_e*H1P + unit4], POISON);
            } else if (unit4 < H2){
                pub8((u64*)&h2s[((it+1)%3)*H2SLOT + (size_t)bg_e*H2P + unit4], POISON);
            }
        }

        if (active){
            // ---- 18 k-step MFMA, weights in VGPR ----
            f32x4 acc0 = {0.f,0.f,0.f,0.f}, acc1 = {0.f,0.f,0.f,0.f};
            #pragma unroll
            for (int ks = 0; ks < 18; ++ks){
                const int off = ((ks*4 + fg) ^ sw) << 3;
                short8 b0 = *(const short8*)(arow0 + off);
                short8 b1 = *(const short8*)(arow1 + off);
                acc0 = __builtin_amdgcn_mfma_f32_16x16x32_bf16(wreg[ks], b0, acc0, 0, 0, 0);
                acc1 = __builtin_amdgcn_mfma_f32_16x16x32_bf16(wreg[ks], b1, acc1, 0, 0, 0);
            }
            // wave-local gate exchange (wave w owns rows 16w..16w+15)
            const int gr = wave*16 + fg*4;
            #pragma unroll
            for (int q = 0; q < 4; ++q){
                gl[(gr+q)*33 + fr]      = acc0[q];
                gl[(gr+q)*33 + 16 + fr] = acc1[q];
            }
            // ---- epilogue + publish ----
            if (lane < 32){
                float hv[4]; unsigned short hb[4];
                #pragma unroll
                for (int i2 = 0; i2 < 4; ++i2){
                    const int r = wave*16 + i2*4;
                    float gi = gl[(r+0)*33 + lane] + bias[r+0];
                    float gf = gl[(r+1)*33 + lane] + bias[r+1];
                    float gg = gl[(r+2)*33 + lane] + bias[r+2];
                    float go = gl[(r+3)*33 + lane] + bias[r+3];
                    float iv = sigf(gi), fv = sigf(gf), cv = tanhf_(gg), ov = sigf(go);
                    float c = fmaf(fv, creg[i2], iv*cv); creg[i2] = c;
                    hv[i2] = ov * tanhf_(c);
                    hb[i2] = f2bf(hv[i2]);
                }
                if (lane < BQC){
                    U8B pv; pv.us[0]=hb[0]; pv.us[1]=hb[1]; pv.us[2]=hb[2]; pv.us[3]=hb[3];
                    if (l1){
                        pub8((u64*)&h1s[((it+1)%3)*H1SLOT + (size_t)bg_e*H1P + unit4], pv.u);
                        if (it == lenl[lane] - 1){           // h_value (fp32 h)
                            float4 q; q.x=hv[0]; q.y=hv[1]; q.z=hv[2]; q.w=hv[3];
                            *(float4*)(out + 30000000 + (size_t)bg_e*H1 + unit4) = q;
                        }
                    } else if (unit4 < H2){
                        pub8((u64*)&h2s[(it%3)*H2SLOT + (size_t)bg_e*H2P + unit4], pv.u);
                        float4 q; q.x=hv[0]; q.y=hv[1]; q.z=hv[2]; q.w=hv[3];
                        *(float4*)(out + (size_t)bg_e*150000 + (size_t)t*300 + unit4) = q;
                    }
                }
            }
        }

        // ---- L1: confirm L2 consumed slot it%3 (o1) before it is poisoned
        //      at iter it+1 (1-iteration slack; off critical path). ----
        if (l1 && coop && (it + 1 < it_end) && tid < 10){
            while (__hip_atomic_load(&flg[8 + tid], __ATOMIC_RELAXED,
                                     __HIP_MEMORY_SCOPE_SYSTEM) < it + 1)
                __builtin_amdgcn_s_sleep(1);
        }

        // ---- B2 (raw): LDS WAR only. Deliberately NO vmcnt drain -- the
        // publish/poison swaps overlap the next iteration's staging/poll
        // (consumers polling an unapplied granule just see POISON and retry).
        asm volatile("s_waitcnt lgkmcnt(0)" ::: "memory");
        __builtin_amdgcn_sched_barrier(0);
        __builtin_amdgcn_s_barrier();
        __builtin_amdgcn_sched_barrier(0);
    }

    if (!coop && lane < 32){
        float* cs = l1 ? c1 : c2;
        #pragma unroll
        for (int i2 = 0; i2 < 4; ++i2) cs[(unit4 + i2)*BQ + bg_e] = creg[i2];
    }
}

extern "C" void kernel_launch(void* const* d_in, const int* in_sizes, int n_in,
                              void* d_out, int out_size, void* d_ws, size_t ws_size,
                              hipStream_t stream) {
    const float* x    = (const float*)d_in[0];
    const int*   lens = (const int*)  d_in[1];
    const float* Wih1 = (const float*)d_in[2];
    const float* Whh1 = (const float*)d_in[3];
    const float* bih1 = (const float*)d_in[4];
    const float* bhh1 = (const float*)d_in[5];
    const float* Wih2 = (const float*)d_in[6];
    const float* Whh2 = (const float*)d_in[7];
    const float* bih2 = (const float*)d_in[8];
    const float* bhh2 = (const float*)d_in[9];
    float* out = (float*)d_out;
    char*  ws  = (char*)d_ws;

    // zero all state/flags every call (deterministic; wipes stale poison), then
    // PRE-POISON h1 slot 1 (published@it=0, read@it=1 -- no in-loop poison
    // opportunity; initial zeros would falsely pass the sentinel poll).
    hipMemsetAsync(d_ws, 0, (size_t)WS_MSET, stream);
    hipMemsetAsync(ws + WS_H1 + H1SLOT*2 /*bytes: slot 1*/, 0xFF,
                   (size_t)H1SLOT*2, stream);

    int ib = 0, ie = TSEQ + 1, coop = 1;
    void* args[] = {(void*)&x, (void*)&lens, (void*)&Wih1, (void*)&Whh1, (void*)&bih1, (void*)&bhh1,
                    (void*)&Wih2, (void*)&Whh2, (void*)&bih2, (void*)&bhh2,
                    (void*)&out, (void*)&ws, (void*)&ib, (void*)&ie, (void*)&coop};
    hipError_t err = hipLaunchCooperativeKernel((const void*)lstm_mfma, dim3(NBLK), dim3(512),
                                                args, 0, stream);
    if (err != hipSuccess) {
        (void)hipGetLastError();   // fall back: one launch per iteration (state in ws)
        for (int it = 0; it <= TSEQ; ++it) {
            hipLaunchKernelGGL(lstm_mfma, dim3(NBLK), dim3(512), 0, stream,
                               x, lens, Wih1, Whh1, bih1, bhh1, Wih2, Whh2, bih2, bhh2,
                               out, ws, it, it + 1, 0);
        }
    }
}